// Round 1
// baseline (2449.008 us; speedup 1.0000x reference)
//
#include <hip/hip_runtime.h>
#include <math.h>

#define NPATH 8192
#define NT    2048

// tanh(x) = 1 - 2/(1+exp(2x)); __expf -> v_mul + v_exp_f32, rcpf -> v_rcp_f32
__device__ __forceinline__ float fast_tanh(float x) {
    float e = __expf(2.0f * x);
    return 1.0f - 2.0f * __builtin_amdgcn_rcpf(1.0f + e);
}

__device__ __forceinline__ float fast_sigmoid(float x) {
    float e = __expf(-x);
    return __builtin_amdgcn_rcpf(1.0f + e);
}

__global__ __launch_bounds__(256) void nrs_kernel(
    const float* __restrict__ init_var,
    const float* __restrict__ sig,
    const float* __restrict__ dW,
    const float* __restrict__ dtp,
    const float* __restrict__ drw1, const float* __restrict__ drb1,
    const float* __restrict__ drw2, const float* __restrict__ drb2,
    const float* __restrict__ drw3, const float* __restrict__ drb3,
    const float* __restrict__ dfw1, const float* __restrict__ dfb1,
    const float* __restrict__ dfw2, const float* __restrict__ dfb2,
    const float* __restrict__ dfw3, const float* __restrict__ dfb3,
    float* __restrict__ out)
{
    const int tid  = threadIdx.x;
    const int wave = tid >> 6;          // 4 waves per block, 1 path per wave
    const int lane = tid & 63;
    const int half = lane >> 5;         // 0 = drift net, 1 = diffusion net
    const int j    = lane & 31;         // hidden unit owned by this lane
    const int path = blockIdx.x * 4 + wave;

    __shared__ float hbuf[4][64];       // per-wave h-exchange slots

    // select this half's network
    const float* w1 = half ? dfw1 : drw1;   // (32,16) row-major
    const float* b1 = half ? dfb1 : drb1;
    const float* w2 = half ? dfw2 : drw2;   // (32,32) row-major
    const float* b2 = half ? dfb2 : drb2;
    const float* w3 = half ? dfw3 : drw3;   // (32,)

    // per-lane static weights
    const float w1v = w1[j * 16 + 15];      // v-column of layer 1
    float w2row[32];
#pragma unroll
    for (int k = 0; k < 32; ++k) w2row[k] = w2[j * 32 + k];
    const float b2j = b2[j];
    const float w3j = w3[j];
    const float b3d = drb3[0];
    const float b3f = dfb3[0];
    const float dt  = dtp[0];

    // precompute time-invariant part of layer 1: b1[j] + sig . W1[j, :15]
    float pre = b1[j];
#pragma unroll
    for (int k = 0; k < 15; ++k) pre += sig[path * 15 + k] * w1[j * 16 + k];

    float iv = init_var[path];
    iv = fminf(fmaxf(iv, 0.005f), 0.2f);
    float lv = logf(iv);

    const float* dwrow = dW + (size_t)path * NT;
    float* outp = out + path;

    float* hb_all = &hbuf[wave][0];
    const float* hb = &hbuf[wave][half * 32];

    for (int t = 0; t < NT; ++t) {
        float v = lv + 4.0f;
        // layer 1
        float a1 = fast_tanh(pre + v * w1v);
        hb_all[lane] = a1;
        __builtin_amdgcn_wave_barrier();
        // layer 2: lane j computes hidden-out j = b2[j] + sum_k W2[j,k] h[k]
        float acc = b2j;
#pragma unroll
        for (int kk = 0; kk < 8; ++kk) {
            float4 hv = *(const float4*)(hb + kk * 4);
            acc += w2row[kk * 4 + 0] * hv.x;
            acc += w2row[kk * 4 + 1] * hv.y;
            acc += w2row[kk * 4 + 2] * hv.z;
            acc += w2row[kk * 4 + 3] * hv.w;
        }
        float a2 = fast_tanh(acc);
        // layer 3: dot over the 32 lanes of this half
        float part = w3j * a2;
        part += __shfl_xor(part, 1);
        part += __shfl_xor(part, 2);
        part += __shfl_xor(part, 4);
        part += __shfl_xor(part, 8);
        part += __shfl_xor(part, 16);
        float other = __shfl_xor(part, 32);   // the other net's scalar
        float zdr = half ? other : part;
        float zdf = half ? part : other;
        float drift     = 3.0f * fast_tanh(zdr + b3d);
        float diffusion = fast_sigmoid(zdf + b3f) + 0.1f;
        float dwv = dwrow[t];
        lv = lv + drift * dt + diffusion * dwv;
        lv = fminf(fmaxf(lv, -7.0f), -0.5f);
        if (lane == 0) outp[(size_t)t * NPATH] = __expf(lv);
    }
}

extern "C" void kernel_launch(void* const* d_in, const int* in_sizes, int n_in,
                              void* d_out, int out_size, void* d_ws, size_t ws_size,
                              hipStream_t stream) {
    const float* init_var = (const float*)d_in[0];
    const float* sig      = (const float*)d_in[1];
    const float* dW       = (const float*)d_in[2];
    const float* dtp      = (const float*)d_in[3];
    const float* drw1     = (const float*)d_in[4];
    const float* drb1     = (const float*)d_in[5];
    const float* drw2     = (const float*)d_in[6];
    const float* drb2     = (const float*)d_in[7];
    const float* drw3     = (const float*)d_in[8];
    const float* drb3     = (const float*)d_in[9];
    const float* dfw1     = (const float*)d_in[10];
    const float* dfb1     = (const float*)d_in[11];
    const float* dfw2     = (const float*)d_in[12];
    const float* dfb2     = (const float*)d_in[13];
    const float* dfw3     = (const float*)d_in[14];
    const float* dfb3     = (const float*)d_in[15];
    float* out = (float*)d_out;

    dim3 grid(NPATH / 4);
    dim3 block(256);
    hipLaunchKernelGGL(nrs_kernel, grid, block, 0, stream,
                       init_var, sig, dW, dtp,
                       drw1, drb1, drw2, drb2, drw3, drb3,
                       dfw1, dfb1, dfw2, dfb2, dfw3, dfb3,
                       out);
}

// Round 2
// 2301.659 us; speedup vs baseline: 1.0640x; 1.0640x over previous
//
#include <hip/hip_runtime.h>
#include <math.h>

#define NPATH 8192
#define NT    2048
#define SFX   2.8853900817779268f   // 2*log2(e)
#define LFX   1.4426950408889634f   // log2(e)

// ws float layout:
// [0]    w1vS[2][32]      = W1[j][15] * SFX
// [64]   w3S[2][32]       (drift: *SFX ; diff: *(-LFX))
// [128]  b2S[2][32]       = b2 * SFX
// [192]  c[4]: c0=-6*dt, c1=3*dt, c2=b3dr*SFX, c3=b3df*(-LFX)
// [256]  w2S[2][32][32]   = W2 * SFX (row-major, no transpose)
__global__ void prep_kernel(const float* __restrict__ drw1,
                            const float* __restrict__ drw2, const float* __restrict__ drb2,
                            const float* __restrict__ drw3, const float* __restrict__ drb3,
                            const float* __restrict__ dfw1,
                            const float* __restrict__ dfw2, const float* __restrict__ dfb2,
                            const float* __restrict__ dfw3, const float* __restrict__ dfb3,
                            const float* __restrict__ dtp, float* __restrict__ ws)
{
    int tid = threadIdx.x;
    for (int i = tid; i < 2048; i += 256) {
        int net = i >> 10, r = i & 1023;
        ws[256 + i] = (net ? dfw2[r] : drw2[r]) * SFX;
    }
    if (tid < 64) {
        int net = tid >> 5, j = tid & 31;
        const float* w1 = net ? dfw1 : drw1;
        ws[tid] = w1[j * 16 + 15] * SFX;
        const float* w3 = net ? dfw3 : drw3;
        ws[64 + tid] = w3[j] * (net ? -LFX : SFX);
        const float* b2 = net ? dfb2 : drb2;
        ws[128 + tid] = b2[j] * SFX;
    }
    if (tid == 0) {
        float dt = dtp[0];
        ws[192] = -6.0f * dt;
        ws[193] =  3.0f * dt;
        ws[194] = drb3[0] * SFX;
        ws[195] = dfb3[0] * (-LFX);
    }
}

template <int IMM>
__device__ __forceinline__ float swz_add(float x) {
    int yi = __builtin_amdgcn_ds_swizzle(__builtin_bit_cast(int, x), IMM);
    return x + __builtin_bit_cast(float, yi);
}

__global__ __launch_bounds__(256, 6) void nrs_kernel(
    const float* __restrict__ init_var,
    const float* __restrict__ sig,
    const float* __restrict__ dW,
    const float* __restrict__ drw1, const float* __restrict__ drb1,
    const float* __restrict__ dfw1, const float* __restrict__ dfb1,
    const float* __restrict__ ws,
    float* __restrict__ out)
{
    const int tid  = threadIdx.x;
    const int wave = tid >> 6;
    const int lane = tid & 63;
    const int half = lane >> 5;
    const int j    = lane & 31;
    const int path = blockIdx.x * 4 + wave;

    __shared__ float hbuf[4][64];
    float* hb_all = &hbuf[wave][0];
    const float* hb = &hbuf[wave][half * 32];

    // prescaled per-lane weights
    const float w1vS = ws[half * 32 + j];
    const float w3S  = ws[64 + half * 32 + j];
    const float b2S  = ws[128 + half * 32 + j];
    const float c0   = ws[192];           // -6*dt
    const float c1   = ws[193];           //  3*dt
    const float b3v  = half ? ws[195] : ws[194];
    float w2row[32];
    const float* w2p = ws + 256 + half * 1024 + j * 32;
#pragma unroll
    for (int k = 0; k < 32; ++k) w2row[k] = w2p[k];

    // time-invariant layer-1 preactivation (prescaled)
    const float* w1 = half ? dfw1 : drw1;
    const float* b1 = half ? dfb1 : drb1;
    float pre = b1[j];
#pragma unroll
    for (int k = 0; k < 15; ++k) pre = fmaf(sig[path * 15 + k], w1[j * 16 + k], pre);
    pre *= SFX;

    float iv = fminf(fmaxf(init_var[path], 0.005f), 0.2f);
    float lv = logf(iv);

    const float* dwrow = dW + (size_t)path * NT;
    float* outp = out + path;

    for (int t = 0; t < NT; ++t) {
        float dwv = dwrow[t];                 // wave-uniform -> s_load
        float dwc = 0.1f * dwv;
        // layer 1
        float v  = lv + 4.0f;
        float x1 = fmaf(v, w1vS, pre);
        float e1 = __builtin_amdgcn_exp2f(x1);
        float a1 = fmaf(__builtin_amdgcn_rcpf(1.0f + e1), -2.0f, 1.0f);
        hb_all[lane] = a1;
        __builtin_amdgcn_wave_barrier();
        // layer 2: 4 split accumulators, broadcast reads from LDS
        float acc0 = b2S, acc1 = 0.0f, acc2 = 0.0f, acc3 = 0.0f;
#pragma unroll
        for (int kk = 0; kk < 8; ++kk) {
            float4 h4 = *(const float4*)(hb + kk * 4);
            acc0 = fmaf(w2row[4 * kk + 0], h4.x, acc0);
            acc1 = fmaf(w2row[4 * kk + 1], h4.y, acc1);
            acc2 = fmaf(w2row[4 * kk + 2], h4.z, acc2);
            acc3 = fmaf(w2row[4 * kk + 3], h4.w, acc3);
        }
        float acc = (acc0 + acc1) + (acc2 + acc3);
        float e2 = __builtin_amdgcn_exp2f(acc);
        float a2 = fmaf(__builtin_amdgcn_rcpf(1.0f + e2), -2.0f, 1.0f);
        // layer 3: per-half reduce (lanes of each half end with their half's sum)
        float part = a2 * w3S;
        part = swz_add<0x041F>(part);   // xor 1
        part = swz_add<0x081F>(part);   // xor 2
        part = swz_add<0x101F>(part);   // xor 4
        part = swz_add<0x201F>(part);   // xor 8
        part = swz_add<0x401F>(part);   // xor 16
        // shared tail: one exp2+rcp serves both drift (half 0) and sigmoid (half 1)
        float x3 = part + b3v;
        float r3 = __builtin_amdgcn_rcpf(1.0f + __builtin_amdgcn_exp2f(x3));
        float ddr = fmaf(r3, c0, c1);         // drift * dt   = 3dt - 6dt*r
        float ddf = fmaf(r3, dwv, dwc);       // (sigmoid+0.1)*dw
        float mine  = half ? ddf : ddr;
        float other = __shfl_xor(mine, 32);
        lv = fminf(fmaxf(lv + mine + other, -7.0f), -0.5f);
        float ev = __builtin_amdgcn_exp2f(lv * LFX);
        if (lane == 0) outp[(size_t)t * NPATH] = ev;
    }
}

extern "C" void kernel_launch(void* const* d_in, const int* in_sizes, int n_in,
                              void* d_out, int out_size, void* d_ws, size_t ws_size,
                              hipStream_t stream) {
    const float* init_var = (const float*)d_in[0];
    const float* sig      = (const float*)d_in[1];
    const float* dW       = (const float*)d_in[2];
    const float* dtp      = (const float*)d_in[3];
    const float* drw1     = (const float*)d_in[4];
    const float* drb1     = (const float*)d_in[5];
    const float* drw2     = (const float*)d_in[6];
    const float* drb2     = (const float*)d_in[7];
    const float* drw3     = (const float*)d_in[8];
    const float* drb3     = (const float*)d_in[9];
    const float* dfw1     = (const float*)d_in[10];
    const float* dfb1     = (const float*)d_in[11];
    const float* dfw2     = (const float*)d_in[12];
    const float* dfb2     = (const float*)d_in[13];
    const float* dfw3     = (const float*)d_in[14];
    const float* dfb3     = (const float*)d_in[15];
    float* out = (float*)d_out;
    float* ws  = (float*)d_ws;

    hipLaunchKernelGGL(prep_kernel, dim3(1), dim3(256), 0, stream,
                       drw1, drw2, drb2, drw3, drb3,
                       dfw1, dfw2, dfb2, dfw3, dfb3, dtp, ws);
    hipLaunchKernelGGL(nrs_kernel, dim3(NPATH / 4), dim3(256), 0, stream,
                       init_var, sig, dW, drw1, drb1, dfw1, dfb1, ws, out);
}

// Round 3
// 1990.427 us; speedup vs baseline: 1.2304x; 1.1564x over previous
//
#include <hip/hip_runtime.h>
#include <math.h>

#define NPATH 8192
#define NT    2048
#define SFX   2.8853900817779268f   // 2*log2(e)
#define LFX   1.4426950408889634f   // log2(e)

typedef float v2f __attribute__((ext_vector_type(2)));

// ws float layout:
// [0]    w1vS[2][32]      = W1[j][15] * SFX
// [64]   w3S[2][32]       (drift: *SFX ; diff: *(-LFX))
// [128]  b2S[2][32]       = b2 * SFX
// [192]  c[4]: c0=-6*dt, c1=3*dt, c2=b3dr*SFX, c3=b3df*(-LFX)
// [256]  w2S[2][32][32]   = W2 * SFX (row-major)
__global__ void prep_kernel(const float* __restrict__ drw1,
                            const float* __restrict__ drw2, const float* __restrict__ drb2,
                            const float* __restrict__ drw3, const float* __restrict__ drb3,
                            const float* __restrict__ dfw1,
                            const float* __restrict__ dfw2, const float* __restrict__ dfb2,
                            const float* __restrict__ dfw3, const float* __restrict__ dfb3,
                            const float* __restrict__ dtp, float* __restrict__ ws)
{
    int tid = threadIdx.x;
    for (int i = tid; i < 2048; i += 256) {
        int net = i >> 10, r = i & 1023;
        ws[256 + i] = (net ? dfw2[r] : drw2[r]) * SFX;
    }
    if (tid < 64) {
        int net = tid >> 5, j = tid & 31;
        const float* w1 = net ? dfw1 : drw1;
        ws[tid] = w1[j * 16 + 15] * SFX;
        const float* w3 = net ? dfw3 : drw3;
        ws[64 + tid] = w3[j] * (net ? -LFX : SFX);
        const float* b2 = net ? dfb2 : drb2;
        ws[128 + tid] = b2[j] * SFX;
    }
    if (tid == 0) {
        float dt = dtp[0];
        ws[192] = -6.0f * dt;
        ws[193] =  3.0f * dt;
        ws[194] = drb3[0] * SFX;
        ws[195] = dfb3[0] * (-LFX);
    }
}

template <int IMM>
__device__ __forceinline__ float swz(float x) {
    int yi = __builtin_amdgcn_ds_swizzle(__builtin_bit_cast(int, x), IMM);
    return __builtin_bit_cast(float, yi);
}

__global__ __launch_bounds__(256, 4) void nrs_kernel(
    const float* __restrict__ init_var,
    const float* __restrict__ sig,
    const float* __restrict__ dW,
    const float* __restrict__ drw1, const float* __restrict__ drb1,
    const float* __restrict__ dfw1, const float* __restrict__ dfb1,
    const float* __restrict__ ws,
    float* __restrict__ out)
{
    const int tid  = threadIdx.x;
    const int wave = tid >> 6;
    const int lane = tid & 63;
    const int hf   = lane >> 5;          // which of the wave's 2 paths
    const int j    = lane & 31;          // hidden unit owned by this lane
    const int path = blockIdx.x * 8 + wave * 2 + hf;

    // per-path h buffer: 32 units x 2 nets interleaved {h_dr[u], h_df[u]}
    __shared__ float hbuf[4][2][64];
    float* hb = &hbuf[wave][hf][0];

    // per-lane statics: unit j of BOTH nets
    const float w1vS0 = ws[j],        w1vS1 = ws[32 + j];
    const float w3S0  = ws[64 + j],   w3S1  = ws[96 + j];
    const float b2S0  = ws[128 + j],  b2S1  = ws[160 + j];
    const float c0 = ws[192], c1 = ws[193];
    const float c23 = (j & 16) ? ws[195] : ws[194];

    // both nets' W2 row j, interleaved as pairs {w_dr[j][k], w_df[j][k]}
    v2f w2i[32];
    {
        const float* pa = ws + 256 + j * 32;
        const float* pb = ws + 256 + 1024 + j * 32;
#pragma unroll
        for (int k = 0; k < 32; ++k) w2i[k] = (v2f){pa[k], pb[k]};
    }

    // time-invariant layer-1 preactivation for unit j, both nets (prescaled)
    float pre0 = drb1[j], pre1 = dfb1[j];
#pragma unroll
    for (int k = 0; k < 15; ++k) {
        float s = sig[path * 15 + k];
        pre0 = fmaf(s, drw1[j * 16 + k], pre0);
        pre1 = fmaf(s, dfw1[j * 16 + k], pre1);
    }
    pre0 *= SFX; pre1 *= SFX;

    float iv = fminf(fmaxf(init_var[path], 0.005f), 0.2f);
    float lv = logf(iv);

    const float* dwrow = dW + (size_t)path * NT;
    float* outp = out + path;

    for (int t = 0; t < NT; ++t) {
        float dwv = dwrow[t];
        // layer 1 (both nets, packed)
        float v  = lv + 4.0f;
        float x10 = fmaf(v, w1vS0, pre0);
        float x11 = fmaf(v, w1vS1, pre1);
        float a10 = fmaf(__builtin_amdgcn_rcpf(1.0f + __builtin_amdgcn_exp2f(x10)), -2.0f, 1.0f);
        float a11 = fmaf(__builtin_amdgcn_rcpf(1.0f + __builtin_amdgcn_exp2f(x11)), -2.0f, 1.0f);
        *(v2f*)(hb + 2 * j) = (v2f){a10, a11};
        __builtin_amdgcn_wave_barrier();
        // layer 2: lane j computes unit-j output of both nets via packed FMA
        v2f accA = (v2f){b2S0, b2S1};
        v2f accB = (v2f){0.0f, 0.0f};
#pragma unroll
        for (int kk = 0; kk < 16; ++kk) {
            float4 h4 = ((const float4*)hb)[kk];   // {h0[2kk],h1[2kk],h0[2kk+1],h1[2kk+1]}
            accA = __builtin_elementwise_fma(w2i[2 * kk],     (v2f){h4.x, h4.y}, accA);
            accB = __builtin_elementwise_fma(w2i[2 * kk + 1], (v2f){h4.z, h4.w}, accB);
        }
        __builtin_amdgcn_wave_barrier();
        v2f s2 = accA + accB;
        float a20 = fmaf(__builtin_amdgcn_rcpf(1.0f + __builtin_amdgcn_exp2f(s2.x)), -2.0f, 1.0f);
        float a21 = fmaf(__builtin_amdgcn_rcpf(1.0f + __builtin_amdgcn_exp2f(s2.y)), -2.0f, 1.0f);
        // layer 3 partials, both nets packed; butterfly over the 32 lanes
        v2f p = (v2f){a20 * w3S0, a21 * w3S1};
        { v2f q; q.x = swz<0x041F>(p.x); q.y = swz<0x041F>(p.y); p += q; }
        { v2f q; q.x = swz<0x081F>(p.x); q.y = swz<0x081F>(p.y); p += q; }
        { v2f q; q.x = swz<0x101F>(p.x); q.y = swz<0x101F>(p.y); p += q; }
        { v2f q; q.x = swz<0x201F>(p.x); q.y = swz<0x201F>(p.y); p += q; }
        { v2f q; q.x = swz<0x401F>(p.x); q.y = swz<0x401F>(p.y); p += q; }
        // shared-exp tail: quarter j<16 does drift, j>=16 does sigmoid
        float x3 = ((j & 16) ? p.y : p.x) + c23;
        float r3 = __builtin_amdgcn_rcpf(1.0f + __builtin_amdgcn_exp2f(x3));
        float dd = (j & 16) ? fmaf(r3, dwv, 0.1f * dwv)   // (sigmoid+0.1)*dw
                            : fmaf(r3, c0, c1);           // drift*dt
        float dlv = dd + swz<0x401F>(dd);                 // exchange across quarters
        lv = fminf(fmaxf(lv + dlv, -7.0f), -0.5f);
        float ev = __builtin_amdgcn_exp2f(lv * LFX);
        if (j == 0) outp[(size_t)t * NPATH] = ev;
    }
}

extern "C" void kernel_launch(void* const* d_in, const int* in_sizes, int n_in,
                              void* d_out, int out_size, void* d_ws, size_t ws_size,
                              hipStream_t stream) {
    const float* init_var = (const float*)d_in[0];
    const float* sig      = (const float*)d_in[1];
    const float* dW       = (const float*)d_in[2];
    const float* dtp      = (const float*)d_in[3];
    const float* drw1     = (const float*)d_in[4];
    const float* drb1     = (const float*)d_in[5];
    const float* drw2     = (const float*)d_in[6];
    const float* drb2     = (const float*)d_in[7];
    const float* drw3     = (const float*)d_in[8];
    const float* drb3     = (const float*)d_in[9];
    const float* dfw1     = (const float*)d_in[10];
    const float* dfb1     = (const float*)d_in[11];
    const float* dfw2     = (const float*)d_in[12];
    const float* dfb2     = (const float*)d_in[13];
    const float* dfw3     = (const float*)d_in[14];
    const float* dfb3     = (const float*)d_in[15];
    float* out = (float*)d_out;
    float* ws  = (float*)d_ws;

    hipLaunchKernelGGL(prep_kernel, dim3(1), dim3(256), 0, stream,
                       drw1, drw2, drb2, drw3, drb3,
                       dfw1, dfw2, dfb2, dfw3, dfb3, dtp, ws);
    hipLaunchKernelGGL(nrs_kernel, dim3(NPATH / 8), dim3(256), 0, stream,
                       init_var, sig, dW, drw1, drb1, dfw1, dfb1, ws, out);
}

// Round 4
// 1931.355 us; speedup vs baseline: 1.2680x; 1.0306x over previous
//
#include <hip/hip_runtime.h>
#include <math.h>

#define NPATH 8192
#define NT    2048
#define SFX   2.8853900817779268f   // 2*log2(e)
#define LFX   1.4426950408889634f   // log2(e)

typedef float v2f __attribute__((ext_vector_type(2)));

// ws float layout:
// [0]    w1vS[2][32]      = W1[j][15] * SFX
// [64]   w3S[2][32]       (drift: *SFX ; diff: *(-LFX))
// [128]  b2S[2][32]       = b2 * SFX
// [192]  c[4]: c0=-6*dt, c1=3*dt, c2=b3dr*SFX, c3=b3df*(-LFX)
// [256]  w2S[2][32][32]   = W2 * SFX (row-major)
__global__ void prep_kernel(const float* __restrict__ drw1,
                            const float* __restrict__ drw2, const float* __restrict__ drb2,
                            const float* __restrict__ drw3, const float* __restrict__ drb3,
                            const float* __restrict__ dfw1,
                            const float* __restrict__ dfw2, const float* __restrict__ dfb2,
                            const float* __restrict__ dfw3, const float* __restrict__ dfb3,
                            const float* __restrict__ dtp, float* __restrict__ ws)
{
    int tid = threadIdx.x;
    for (int i = tid; i < 2048; i += 256) {
        int net = i >> 10, r = i & 1023;
        ws[256 + i] = (net ? dfw2[r] : drw2[r]) * SFX;
    }
    if (tid < 64) {
        int net = tid >> 5, j = tid & 31;
        const float* w1 = net ? dfw1 : drw1;
        ws[tid] = w1[j * 16 + 15] * SFX;
        const float* w3 = net ? dfw3 : drw3;
        ws[64 + tid] = w3[j] * (net ? -LFX : SFX);
        const float* b2 = net ? dfb2 : drb2;
        ws[128 + tid] = b2[j] * SFX;
    }
    if (tid == 0) {
        float dt = dtp[0];
        ws[192] = -6.0f * dt;
        ws[193] =  3.0f * dt;
        ws[194] = drb3[0] * SFX;
        ws[195] = dfb3[0] * (-LFX);
    }
}

template <int IMM>
__device__ __forceinline__ float swz(float x) {
    int yi = __builtin_amdgcn_ds_swizzle(__builtin_bit_cast(int, x), IMM);
    return __builtin_bit_cast(float, yi);
}

__global__ __launch_bounds__(256, 4) void nrs_kernel(
    const float* __restrict__ init_var,
    const float* __restrict__ sig,
    const float* __restrict__ dW,
    const float* __restrict__ drw1, const float* __restrict__ drb1,
    const float* __restrict__ dfw1, const float* __restrict__ dfb1,
    const float* __restrict__ ws,
    float* __restrict__ out)
{
    const int tid  = threadIdx.x;
    const int wave = tid >> 6;
    const int lane = tid & 63;
    const int hf   = lane >> 5;          // which of the wave's 2 paths
    const int j    = lane & 31;          // hidden unit owned by this lane
    const int path = blockIdx.x * 8 + wave * 2 + hf;

    // per-path h buffer: 32 units x 2 nets interleaved {h_dr[u], h_df[u]}
    __shared__ float hbuf[4][2][64];
    float* hb = &hbuf[wave][hf][0];

    // per-lane statics: unit j of BOTH nets
    const float w1vS0 = ws[j],        w1vS1 = ws[32 + j];
    const float w3S0  = ws[64 + j],   w3S1  = ws[96 + j];
    const float b2S0  = ws[128 + j],  b2S1  = ws[160 + j];
    const float c0 = ws[192], c1 = ws[193];
    const float c23 = (j & 16) ? ws[195] : ws[194];

    // time-invariant layer-1 preactivation for unit j, both nets (prescaled)
    float pre0 = drb1[j], pre1 = dfb1[j];
#pragma unroll
    for (int k = 0; k < 15; ++k) {
        float s = sig[path * 15 + k];
        pre0 = fmaf(s, drw1[j * 16 + k], pre0);
        pre1 = fmaf(s, dfw1[j * 16 + k], pre1);
    }
    pre0 *= SFX; pre1 *= SFX;

    float iv = fminf(fmaxf(init_var[path], 0.005f), 0.2f);
    float lv = logf(iv);

    // both nets' W2 row j, interleaved as pairs {w_dr[j][k], w_df[j][k]}.
    // Loaded AFTER the prologue; asm touch forbids rematerialization so the
    // 32 v2f (64 VGPRs) stay register-resident across the step loop.
    v2f w2i[32];
    {
        const float* pa = ws + 256 + j * 32;
        const float* pb = ws + 256 + 1024 + j * 32;
#pragma unroll
        for (int k = 0; k < 32; ++k) w2i[k] = (v2f){pa[k], pb[k]};
    }
#pragma unroll
    for (int k = 0; k < 32; ++k) asm volatile("" : "+v"(w2i[k]));

    const float* dwrow = dW + (size_t)path * NT;
    float* outp = out + path;

    float dwv = dwrow[0];
    for (int t = 0; t < NT; ++t) {
        float dwv_next = (t + 1 < NT) ? dwrow[t + 1] : 0.0f;
        // layer 1 (both nets)
        float v  = lv + 4.0f;
        float x10 = fmaf(v, w1vS0, pre0);
        float x11 = fmaf(v, w1vS1, pre1);
        float a10 = fmaf(__builtin_amdgcn_rcpf(1.0f + __builtin_amdgcn_exp2f(x10)), -2.0f, 1.0f);
        float a11 = fmaf(__builtin_amdgcn_rcpf(1.0f + __builtin_amdgcn_exp2f(x11)), -2.0f, 1.0f);
        *(v2f*)(hb + 2 * j) = (v2f){a10, a11};
        __builtin_amdgcn_wave_barrier();
        // layer 2: lane j computes unit-j output of both nets via packed FMA
        v2f accA = (v2f){b2S0, b2S1};
        v2f accB = (v2f){0.0f, 0.0f};
#pragma unroll
        for (int kk = 0; kk < 16; ++kk) {
            float4 h4 = ((const float4*)hb)[kk];   // {h0[2kk],h1[2kk],h0[2kk+1],h1[2kk+1]}
            accA = __builtin_elementwise_fma(w2i[2 * kk],     (v2f){h4.x, h4.y}, accA);
            accB = __builtin_elementwise_fma(w2i[2 * kk + 1], (v2f){h4.z, h4.w}, accB);
        }
        __builtin_amdgcn_wave_barrier();
        v2f s2 = accA + accB;
        float a20 = fmaf(__builtin_amdgcn_rcpf(1.0f + __builtin_amdgcn_exp2f(s2.x)), -2.0f, 1.0f);
        float a21 = fmaf(__builtin_amdgcn_rcpf(1.0f + __builtin_amdgcn_exp2f(s2.y)), -2.0f, 1.0f);
        // layer 3: pack-select then 5-stage scalar reduce (6 swizzles total)
        float px = a20 * w3S0;                 // drift partial
        float py = a21 * w3S1;                 // diffusion partial
        float m  = (j & 16) ? py : px;         // my quarter's component
        float n  = (j & 16) ? px : py;         // the other quarter's component
        float u  = m + swz<0x401F>(n);         // xor16: fold 32 lanes -> 16 per net
        u += swz<0x041F>(u);                   // xor 1
        u += swz<0x081F>(u);                   // xor 2
        u += swz<0x101F>(u);                   // xor 4
        u += swz<0x201F>(u);                   // xor 8
        // lanes j<16: full drift sum; j>=16: full diffusion sum
        float x3 = u + c23;
        float r3 = __builtin_amdgcn_rcpf(1.0f + __builtin_amdgcn_exp2f(x3));
        float dd = (j & 16) ? fmaf(r3, dwv, 0.1f * dwv)   // (sigmoid+0.1)*dw
                            : fmaf(r3, c0, c1);           // drift*dt
        float dlv = dd + swz<0x401F>(dd);                 // exchange across quarters
        lv = fminf(fmaxf(lv + dlv, -7.0f), -0.5f);
        float ev = __builtin_amdgcn_exp2f(lv * LFX);
        if (j == 0) outp[(size_t)t * NPATH] = ev;
        dwv = dwv_next;
    }
}

extern "C" void kernel_launch(void* const* d_in, const int* in_sizes, int n_in,
                              void* d_out, int out_size, void* d_ws, size_t ws_size,
                              hipStream_t stream) {
    const float* init_var = (const float*)d_in[0];
    const float* sig      = (const float*)d_in[1];
    const float* dW       = (const float*)d_in[2];
    const float* dtp      = (const float*)d_in[3];
    const float* drw1     = (const float*)d_in[4];
    const float* drb1     = (const float*)d_in[5];
    const float* drw2     = (const float*)d_in[6];
    const float* drb2     = (const float*)d_in[7];
    const float* drw3     = (const float*)d_in[8];
    const float* drb3     = (const float*)d_in[9];
    const float* dfw1     = (const float*)d_in[10];
    const float* dfb1     = (const float*)d_in[11];
    const float* dfw2     = (const float*)d_in[12];
    const float* dfb2     = (const float*)d_in[13];
    const float* dfw3     = (const float*)d_in[14];
    const float* dfb3     = (const float*)d_in[15];
    float* out = (float*)d_out;
    float* ws  = (float*)d_ws;

    hipLaunchKernelGGL(prep_kernel, dim3(1), dim3(256), 0, stream,
                       drw1, drw2, drb2, drw3, drb3,
                       dfw1, dfw2, dfb2, dfw3, dfb3, dtp, ws);
    hipLaunchKernelGGL(nrs_kernel, dim3(NPATH / 8), dim3(256), 0, stream,
                       init_var, sig, dW, drw1, drb1, dfw1, dfb1, ws, out);
}

// Round 6
// 871.401 us; speedup vs baseline: 2.8104x; 2.2164x over previous
//
#include <hip/hip_runtime.h>
#include <math.h>

#define NPATH 8192
#define NT    2048
#define NODES 384
#define VMIN  (-3.06f)
#define WIDTHV 6.62f            // VMAX - VMIN = 3.56 - (-3.06)
#define SFX   2.8853900817779268f   // 2*log2(e)
#define LFX   1.4426950408889634f   // log2(e)

typedef float v2f __attribute__((ext_vector_type(2)));
typedef float v4f __attribute__((ext_vector_type(4)));

// ws float layout
#define W2P_F   0        // v2f w2pairs[k*32+j] = {W2dr[j][k], W2df[j][k]}  (2048 floats)
#define W1VP_F  2048     // v2f w1v pairs [32]
#define W3P_F   2112     // v2f w3 pairs  [32]
#define B2P_F   2176     // v2f b2 pairs  [32]
#define CST_F   2240     // b3dr, b3df, dt
#define TAB_F   4096     // v2f table[path*NODES + node] = {drift*dt, diffusion}

__device__ __forceinline__ v2f vsplat(float x) { return (v2f){x, x}; }
__device__ __forceinline__ v2f vfma(v2f a, v2f b, v2f c) { return __builtin_elementwise_fma(a, b, c); }

__device__ __forceinline__ float tanh1(float z) {   // tanh(z) via exp2
    float e = __builtin_amdgcn_exp2f(SFX * z);
    return fmaf(__builtin_amdgcn_rcpf(1.0f + e), -2.0f, 1.0f);
}
__device__ __forceinline__ float sig1(float z) {    // sigmoid(z)
    float e = __builtin_amdgcn_exp2f(-LFX * z);
    return __builtin_amdgcn_rcpf(1.0f + e);
}
__device__ __forceinline__ v2f tanh2(v2f z) {
    v2f r; r.x = tanh1(z.x); r.y = tanh1(z.y); return r;
}

__global__ void prep_kernel(const float* __restrict__ drw1,
                            const float* __restrict__ drw2, const float* __restrict__ drb2,
                            const float* __restrict__ drw3, const float* __restrict__ drb3,
                            const float* __restrict__ dfw1,
                            const float* __restrict__ dfw2, const float* __restrict__ dfb2,
                            const float* __restrict__ dfw3, const float* __restrict__ dfb3,
                            const float* __restrict__ dtp, float* __restrict__ ws)
{
    int tid = threadIdx.x;
    for (int idx = tid; idx < 1024; idx += 256) {
        int k = idx >> 5, j = idx & 31;
        ws[W2P_F + 2 * idx]     = drw2[j * 32 + k];   // W2[j][k] pairs, k-major
        ws[W2P_F + 2 * idx + 1] = dfw2[j * 32 + k];
    }
    if (tid < 32) {
        ws[W1VP_F + 2 * tid]     = drw1[tid * 16 + 15];
        ws[W1VP_F + 2 * tid + 1] = dfw1[tid * 16 + 15];
        ws[W3P_F + 2 * tid]      = drw3[tid];
        ws[W3P_F + 2 * tid + 1]  = dfw3[tid];
        ws[B2P_F + 2 * tid]      = drb2[tid];
        ws[B2P_F + 2 * tid + 1]  = dfb2[tid];
    }
    if (tid == 0) {
        ws[CST_F]     = drb3[0];
        ws[CST_F + 1] = dfb3[0];
        ws[CST_F + 2] = dtp[0];
    }
}

// One block per path (384 lanes = 384 v-nodes). Each lane evaluates both nets
// fully at its node: weights come in as wave-uniform scalar loads of {dr,df}
// pairs -> v_pk_fma_f32; per-path layer-1 constants computed cooperatively.
__global__ __attribute__((amdgpu_flat_work_group_size(NODES, NODES), amdgpu_waves_per_eu(2, 4)))
void build_kernel(const float* __restrict__ sig,
                  const float* __restrict__ drw1, const float* __restrict__ drb1,
                  const float* __restrict__ dfw1, const float* __restrict__ dfb1,
                  float* __restrict__ ws)
{
    const int p = blockIdx.x;
    const int i = threadIdx.x;
    __shared__ v2f spv[32];            // pre pairs {dr, df} per hidden unit
    if (i < 64) {
        int j = i & 31, net = i >> 5;
        const float* w1 = net ? dfw1 : drw1;
        const float* b1 = net ? dfb1 : drb1;
        float acc = b1[j];
#pragma unroll
        for (int m = 0; m < 15; ++m) acc = fmaf(sig[p * 15 + m], w1[j * 16 + m], acc);
        ((float*)spv)[2 * j + net] = acc;
    }
    __syncthreads();

    const float v = VMIN + (WIDTHV / (float)(NODES - 1)) * (float)i;
    const v2f* __restrict__ w2p  = (const v2f*)(ws + W2P_F);
    const v2f* __restrict__ w1vp = (const v2f*)(ws + W1VP_F);
    const v2f* __restrict__ w3p  = (const v2f*)(ws + W3P_F);
    const v2f* __restrict__ b2p  = (const v2f*)(ws + B2P_F);

    v2f acc2[32];
#pragma unroll
    for (int j = 0; j < 32; ++j) acc2[j] = b2p[j];

#pragma unroll 4
    for (int k = 0; k < 32; ++k) {
        v2f pre = spv[k];                          // LDS broadcast
        v2f z   = vfma(vsplat(v), w1vp[k], pre);
        v2f h   = tanh2(z);
        const v2f* col = w2p + k * 32;             // uniform scalar loads
#pragma unroll
        for (int j = 0; j < 32; ++j) acc2[j] = vfma(col[j], h, acc2[j]);
    }

    v2f z3 = (v2f){ws[CST_F], ws[CST_F + 1]};
#pragma unroll
    for (int j = 0; j < 32; ++j) {
        v2f a2 = tanh2(acc2[j]);
        z3 = vfma(w3p[j], a2, z3);
    }
    float dt = ws[CST_F + 2];
    float fv = 3.0f * tanh1(z3.x) * dt;            // drift * dt
    float gv = sig1(z3.y) + 0.1f;                  // diffusion
    ((v2f*)(ws + TAB_F))[(size_t)p * NODES + i] = (v2f){fv, gv};
}

// One lane per path. Per step: Catmull-Rom lookup of {drift*dt, diffusion}
// from the per-path table (L2-resident), then the scalar recurrence.
__global__ __launch_bounds__(64) void scan_kernel(
    const float* __restrict__ init_var,
    const float* __restrict__ dW,
    const float* __restrict__ ws,
    float* __restrict__ out)
{
    const int path = blockIdx.x * 64 + threadIdx.x;
    float lv = logf(fminf(fmaxf(init_var[path], 0.005f), 0.2f));
    const v2f* __restrict__ tp = (const v2f*)(ws + TAB_F) + (size_t)path * NODES;
    const float* __restrict__ dwrow = dW + (size_t)path * NT;
    float* __restrict__ outp = out + path;

    const float INVD = (float)(NODES - 1) / WIDTHV;
    const float UOFF = (4.0f - VMIN) * INVD;       // u = lv*INVD + UOFF

    auto STEP = [&](float dw, int tt) {
        float u  = fmaf(lv, INVD, UOFF);
        float fi = floorf(u);
        int   i  = (int)fi;
        float w  = u - fi;
        i = i < 1 ? 1 : (i > NODES - 3 ? NODES - 3 : i);
        const v2f* n = tp + i;
        v2f m1 = n[-1], p0 = n[0], p1 = n[1], p2 = n[2];
        // warm L1 for the next step's (nearby) window
        int ipa = i > 9 ? i - 9 : 0;
        int ipb = i < NODES - 11 ? i + 10 : NODES - 1;
        v2f pfa = tp[ipa], pfb = tp[ipb];
        asm volatile("" :: "v"(pfa), "v"(pfb));
        // Catmull-Rom: p0 + 0.5w*(d + w*(c2 + w*c3))
        v2f d  = p1 - m1;
        v2f c2 = (m1 + m1) - vsplat(5.0f) * p0 + vsplat(4.0f) * p1 - p2;
        v2f c3 = vsplat(3.0f) * (p0 - p1) + (p2 - m1);
        v2f val = vfma(vsplat(0.5f * w), vfma(vsplat(w), vfma(vsplat(w), c3, c2), d), p0);
        lv += fmaf(val.y, dw, val.x);
        lv = fminf(fmaxf(lv, -7.0f), -0.5f);
        float ev = __builtin_amdgcn_exp2f(lv * LFX);
        __builtin_nontemporal_store(ev, outp + (size_t)tt * NPATH);
    };

    v4f dwc = __builtin_nontemporal_load((const v4f*)dwrow);
    for (int t = 0; t < NT; t += 4) {
        v4f dwn = {0.0f, 0.0f, 0.0f, 0.0f};
        if (t + 4 < NT) dwn = __builtin_nontemporal_load((const v4f*)(dwrow + t + 4));
        STEP(dwc.x, t);
        STEP(dwc.y, t + 1);
        STEP(dwc.z, t + 2);
        STEP(dwc.w, t + 3);
        dwc = dwn;
    }
}

extern "C" void kernel_launch(void* const* d_in, const int* in_sizes, int n_in,
                              void* d_out, int out_size, void* d_ws, size_t ws_size,
                              hipStream_t stream) {
    const float* init_var = (const float*)d_in[0];
    const float* sig      = (const float*)d_in[1];
    const float* dW       = (const float*)d_in[2];
    const float* dtp      = (const float*)d_in[3];
    const float* drw1     = (const float*)d_in[4];
    const float* drb1     = (const float*)d_in[5];
    const float* drw2     = (const float*)d_in[6];
    const float* drb2     = (const float*)d_in[7];
    const float* drw3     = (const float*)d_in[8];
    const float* drb3     = (const float*)d_in[9];
    const float* dfw1     = (const float*)d_in[10];
    const float* dfb1     = (const float*)d_in[11];
    const float* dfw2     = (const float*)d_in[12];
    const float* dfb2     = (const float*)d_in[13];
    const float* dfw3     = (const float*)d_in[14];
    const float* dfb3     = (const float*)d_in[15];
    float* out = (float*)d_out;
    float* ws  = (float*)d_ws;

    hipLaunchKernelGGL(prep_kernel, dim3(1), dim3(256), 0, stream,
                       drw1, drw2, drb2, drw3, drb3,
                       dfw1, dfw2, dfb2, dfw3, dfb3, dtp, ws);
    hipLaunchKernelGGL(build_kernel, dim3(NPATH), dim3(NODES), 0, stream,
                       sig, drw1, drb1, dfw1, dfb1, ws);
    hipLaunchKernelGGL(scan_kernel, dim3(NPATH / 64), dim3(64), 0, stream,
                       init_var, dW, ws, out);
}